// Round 1
// baseline (74.858 us; speedup 1.0000x reference)
//
#include <hip/hip_runtime.h>
#include <math.h>

#define BB   512
#define CC   3
#define HH   64
#define WW   32
#define HOUT 38
#define WOUT 16
#define HID  128
#define DD   114          // CC*HOUT
#define DP   116          // padded row for seq (16B-aligned rows: 116*4=464)
#define NPOOL (CC*HOUT*WOUT) // 1824

// ---------------- Kernel 1: pool + gelu + s_mean + 16-step RNN + t_mean ----
// one block per batch element, 128 threads (thread = hid index k)
__global__ __launch_bounds__(128, 1)
void k1_fused(const float* __restrict__ x,
              const float* __restrict__ Wih,   // [HID][DD]
              const float* __restrict__ Whh,   // [HID][HID]
              const float* __restrict__ bih,   // [HID]
              const float* __restrict__ bhh,   // [HID]
              float* __restrict__ s_mean,      // [BB]
              float* __restrict__ t_mean)      // [BB][HID]
{
    __shared__ __align__(16) float xl[CC*HH*WW];    // 6144 f = 24 KB
    __shared__ __align__(16) float seq[WOUT][DP];   // 16x116 = 7.4 KB
    __shared__ __align__(16) float hbuf[2][HID];    // 1 KB
    __shared__ float red[128];
    __shared__ int   rowl[HOUT];

    const int tid = threadIdx.x;
    const int b   = blockIdx.x;

    // fractional-pool row starts, exact IEEE-f64 match with the numpy formula
    if (tid < HOUT) {
        double alpha = (double)(HH - 2) / (double)(HOUT - 1);
        rowl[tid] = (tid < HOUT - 1)
            ? (int)(floor((tid + 0.5) * alpha) - floor(0.5 * alpha))
            : (HH - 2);
    }

    // stage x[b] into LDS, coalesced float4
    {
        const float4* xg  = (const float4*)(x + (size_t)b * (CC*HH*WW));
        float4*       xl4 = (float4*)xl;
        #pragma unroll
        for (int i = 0; i < (CC*HH*WW/4)/128; ++i)
            xl4[tid + 128*i] = xg[tid + 128*i];
    }
    __syncthreads();

    // pool (max over 2x2 fractional windows) + exact GELU -> seq[t][d]
    float psum = 0.f;
    for (int idx = tid; idx < NPOOL; idx += 128) {
        int c  = idx / (HOUT*WOUT);
        int r  = idx % (HOUT*WOUT);
        int ho = r / WOUT;
        int wo = r % WOUT;
        int r0 = rowl[ho];
        int c0 = 2 * wo;                       // COL[wo] == 2*wo exactly
        const float* p0 = &xl[c*(HH*WW) + r0*WW + c0];
        float m = fmaxf(fmaxf(p0[0], p0[1]), fmaxf(p0[WW], p0[WW+1]));
        psum += m;
        float a = 0.5f * m * (1.f + erff(m * 0.70710678118654752440f));
        seq[wo][c*HOUT + ho] = a;              // d = c*38 + ho (C-major flatten)
    }
    if (tid < WOUT) { seq[tid][114] = 0.f; seq[tid][115] = 0.f; }
    hbuf[0][tid] = 0.f;                        // h_0 = 0 (tid covers HID)

    // block-reduce spatial sum of pooled -> s_mean[b]
    red[tid] = psum;
    __syncthreads();                           // also fences seq/hbuf writes
    #pragma unroll
    for (int s = 64; s > 0; s >>= 1) {
        if (tid < s) red[tid] += red[tid + s];
        __syncthreads();
    }
    if (tid == 0) s_mean[b] = red[0] / (float)NPOOL;

    // weights for row k into registers (static indexing only -> stays in VGPRs)
    const int k = tid;
    float4 wih[29];
    #pragma unroll
    for (int dd = 0; dd < 29; ++dd) {
        float v0 = (4*dd+0 < DD) ? Wih[k*DD + 4*dd+0] : 0.f;
        float v1 = (4*dd+1 < DD) ? Wih[k*DD + 4*dd+1] : 0.f;
        float v2 = (4*dd+2 < DD) ? Wih[k*DD + 4*dd+2] : 0.f;
        float v3 = (4*dd+3 < DD) ? Wih[k*DD + 4*dd+3] : 0.f;
        wih[dd] = make_float4(v0, v1, v2, v3);
    }
    float4 whh[32];
    {
        const float4* wr = (const float4*)(Whh + k*HID);  // rows 16B-aligned
        #pragma unroll
        for (int dd = 0; dd < 32; ++dd) whh[dd] = wr[dd];
    }
    const float bias = bih[k] + bhh[k];

    // 16-step recurrence; seq/h rows read as LDS float4 broadcasts
    float hsum = 0.f;
    for (int t = 0; t < WOUT; ++t) {
        float u = bias;
        const float4* s4 = (const float4*)seq[t];
        #pragma unroll
        for (int dd = 0; dd < 29; ++dd) {
            float4 sv = s4[dd];
            u += wih[dd].x*sv.x + wih[dd].y*sv.y + wih[dd].z*sv.z + wih[dd].w*sv.w;
        }
        const float4* h4 = (const float4*)hbuf[t & 1];
        #pragma unroll
        for (int dd = 0; dd < 32; ++dd) {
            float4 hv = h4[dd];
            u += whh[dd].x*hv.x + whh[dd].y*hv.y + whh[dd].z*hv.z + whh[dd].w*hv.w;
        }
        float hn = tanhf(u);
        hsum += hn;
        hbuf[(t + 1) & 1][k] = hn;
        __syncthreads();
    }
    t_mean[b*HID + k] = tanhf(hsum * (1.f / 16.f));
}

// ---------------- Kernel 2: out[i,0,j,k] = s_mean[i] * t_mean[j,k] ----------
__global__ __launch_bounds__(256)
void k2_out(const float* __restrict__ s_mean,
            const float* __restrict__ t_mean,
            float4* __restrict__ out)
{
    const int total = BB * BB * HID / 4;       // 8,388,608 float4
    const float4* t4 = (const float4*)t_mean;
    const int stride = gridDim.x * blockDim.x;
    for (int g = blockIdx.x * blockDim.x + threadIdx.x; g < total; g += stride) {
        int i = g >> 14;                       // BB*HID/4 = 16384 f4 per i
        int r = g & 16383;
        float s = s_mean[i];
        float4 t = t4[r];
        out[g] = make_float4(s*t.x, s*t.y, s*t.z, s*t.w);
    }
}

extern "C" void kernel_launch(void* const* d_in, const int* in_sizes, int n_in,
                              void* d_out, int out_size, void* d_ws, size_t ws_size,
                              hipStream_t stream)
{
    const float* x   = (const float*)d_in[0];
    const float* Wih = (const float*)d_in[1];
    const float* Whh = (const float*)d_in[2];
    const float* bih = (const float*)d_in[3];
    const float* bhh = (const float*)d_in[4];

    float* ws      = (float*)d_ws;
    float* s_mean  = ws;           // 512 floats
    float* t_mean  = ws + 512;     // 65536 floats (16B-aligned: offset 2048 B)

    k1_fused<<<dim3(BB), dim3(128), 0, stream>>>(x, Wih, Whh, bih, bhh, s_mean, t_mean);
    k2_out<<<dim3(2048), dim3(256), 0, stream>>>(s_mean, t_mean, (float4*)d_out);
}

// Round 3
// 67.087 us; speedup vs baseline: 1.1158x; 1.1158x over previous
//
#include <hip/hip_runtime.h>
#include <math.h>

#define BB   512
#define CC   3
#define HH   64
#define WW   32
#define HOUT 38
#define WOUT 16
#define HID  128
#define DD   114          // CC*HOUT
#define DP   116          // padded act row (116*4B = 464 B, 16B-aligned)
#define NPOOL (CC*HOUT*WOUT) // 1824

typedef float f32x4 __attribute__((ext_vector_type(4)));

// ws layout (floats)
#define WS_SMEAN 0
#define WS_TMEAN 512
#define WS_ACT   (512 + BB*HID)                  // 66048;  act[t][b][DP]
#define WS_Z     (WS_ACT + WOUT*BB*DP)           // 1016320; Z[t][b][HID]

// ---------------- k1a: pool + exact GELU + s_mean -------------------------
__global__ __launch_bounds__(256)
void k1a_pool(const float* __restrict__ x, float* __restrict__ act,
              float* __restrict__ s_mean)
{
    __shared__ __align__(16) float xl[CC*HH*WW];   // 24 KB
    __shared__ float red[256];
    __shared__ int   rowl[HOUT];

    const int tid = threadIdx.x;
    const int b   = blockIdx.x;

    if (tid < HOUT) {
        double alpha = (double)(HH - 2) / (double)(HOUT - 1);
        rowl[tid] = (tid < HOUT - 1)
            ? (int)(floor((tid + 0.5) * alpha) - floor(0.5 * alpha))
            : (HH - 2);
    }
    {
        const float4* xg  = (const float4*)(x + (size_t)b * (CC*HH*WW));
        float4*       xl4 = (float4*)xl;
        #pragma unroll
        for (int i = 0; i < (CC*HH*WW/4)/256; ++i)
            xl4[tid + 256*i] = xg[tid + 256*i];
    }
    // zero the 2 pad lanes of each of the 16 act rows for this b
    if (tid < 32) {
        int t = tid >> 1, d = DD + (tid & 1);
        act[(size_t)(t*BB + b)*DP + d] = 0.f;
    }
    __syncthreads();

    float psum = 0.f;
    for (int idx = tid; idx < NPOOL; idx += 256) {
        int c  = idx / (HOUT*WOUT);
        int r  = idx % (HOUT*WOUT);
        int ho = r / WOUT;
        int wo = r % WOUT;
        const float* p0 = &xl[c*(HH*WW) + rowl[ho]*WW + 2*wo];
        float m = fmaxf(fmaxf(p0[0], p0[1]), fmaxf(p0[WW], p0[WW+1]));
        psum += m;
        float a = 0.5f * m * (1.f + erff(m * 0.70710678118654752440f));
        act[(size_t)(wo*BB + b)*DP + c*HOUT + ho] = a;
    }
    red[tid] = psum;
    __syncthreads();
    #pragma unroll
    for (int s = 128; s > 0; s >>= 1) {
        if (tid < s) red[tid] += red[tid + s];
        __syncthreads();
    }
    if (tid == 0) s_mean[b] = red[0] / (float)NPOOL;
}

// ---------------- k1b: Z[t][b][k] = act[t][b][:] . Wih[k][:] + bias -------
// grid: (64 bgroups, 16 t), 128 threads (thread = k), 8 batches per block
#define GBAT 8
__global__ __launch_bounds__(128)
void k1b_proj(const float* __restrict__ act, const float* __restrict__ Wih,
              const float* __restrict__ bih, const float* __restrict__ bhh,
              float* __restrict__ Z)
{
    __shared__ __align__(16) float actl[GBAT][DP];  // 3.7 KB

    const int k  = threadIdx.x;
    const int bg = blockIdx.x;
    const int t  = blockIdx.y;

    // Wih row k into registers (zero-padded to 116)
    float4 wih[29];
    #pragma unroll
    for (int dd = 0; dd < 28; ++dd) {
        const float* p = Wih + k*DD + 4*dd;
        wih[dd] = make_float4(p[0], p[1], p[2], p[3]);
    }
    wih[28] = make_float4(Wih[k*DD + 112], Wih[k*DD + 113], 0.f, 0.f);
    const float bias = bih[k] + bhh[k];

    // stage 8 act rows (contiguous 928 floats, 16B-aligned)
    {
        const float4* src = (const float4*)(act + (size_t)(t*BB + bg*GBAT)*DP);
        float4*       dst = (float4*)&actl[0][0];
        #pragma unroll
        for (int i = 0; i < (GBAT*DP/4)/128 + 1; ++i) {
            int j = k + 128*i;
            if (j < GBAT*DP/4) dst[j] = src[j];
        }
    }
    __syncthreads();

    #pragma unroll
    for (int r = 0; r < GBAT; ++r) {
        const float4* a4 = (const float4*)actl[r];
        float s0 = 0.f, s1 = 0.f, s2 = 0.f, s3 = 0.f;
        #pragma unroll
        for (int dd = 0; dd < 29; ++dd) {
            float4 a = a4[dd];
            s0 = fmaf(wih[dd].x, a.x, s0);
            s1 = fmaf(wih[dd].y, a.y, s1);
            s2 = fmaf(wih[dd].z, a.z, s2);
            s3 = fmaf(wih[dd].w, a.w, s3);
        }
        Z[(size_t)(t*BB + bg*GBAT + r)*HID + k] = bias + ((s0+s1)+(s2+s3));
    }
}

// ---------------- k1c: 16-step recurrence + t_mean ------------------------
__global__ __launch_bounds__(128)
void k1c_rnn(const float* __restrict__ Z, const float* __restrict__ Whh,
             float* __restrict__ t_mean)
{
    __shared__ __align__(16) float Zl[WOUT][HID];   // 8 KB
    __shared__ __align__(16) float hbuf[2][HID];

    const int k = threadIdx.x;
    const int b = blockIdx.x;

    float4 whh[32];
    {
        const float4* wr = (const float4*)(Whh + k*HID);
        #pragma unroll
        for (int dd = 0; dd < 32; ++dd) whh[dd] = wr[dd];
    }
    #pragma unroll
    for (int t = 0; t < WOUT; ++t)
        Zl[t][k] = Z[(size_t)(t*BB + b)*HID + k];
    hbuf[0][k] = 0.f;
    __syncthreads();

    float hsum = 0.f;
    #pragma unroll
    for (int t = 0; t < WOUT; ++t) {
        const float4* h4 = (const float4*)hbuf[t & 1];
        float s0 = 0.f, s1 = 0.f, s2 = 0.f, s3 = 0.f;
        #pragma unroll
        for (int dd = 0; dd < 32; ++dd) {
            float4 hv = h4[dd];
            s0 = fmaf(whh[dd].x, hv.x, s0);
            s1 = fmaf(whh[dd].y, hv.y, s1);
            s2 = fmaf(whh[dd].z, hv.z, s2);
            s3 = fmaf(whh[dd].w, hv.w, s3);
        }
        float hn = tanhf(Zl[t][k] + ((s0+s1)+(s2+s3)));
        hsum += hn;
        hbuf[(t + 1) & 1][k] = hn;
        __syncthreads();
    }
    t_mean[b*HID + k] = tanhf(hsum * (1.f / 16.f));
}

// ---------------- k2: out[i,0,j,k] = s_mean[i] * t_mean[j,k] --------------
__global__ __launch_bounds__(256)
void k2_out(const float* __restrict__ s_mean,
            const float* __restrict__ t_mean,
            f32x4* __restrict__ out)
{
    const int total = BB * BB * HID / 4;        // 8,388,608 float4
    const f32x4* t4 = (const f32x4*)t_mean;
    const int stride = gridDim.x * blockDim.x;
    for (int g = blockIdx.x * blockDim.x + threadIdx.x; g < total; g += stride) {
        int i = g >> 14;                        // 16384 f4 per i
        int r = g & 16383;
        float s = s_mean[i];
        f32x4 t = t4[r];
        f32x4 v = s * t;
        __builtin_nontemporal_store(v, &out[g]);
    }
}

extern "C" void kernel_launch(void* const* d_in, const int* in_sizes, int n_in,
                              void* d_out, int out_size, void* d_ws, size_t ws_size,
                              hipStream_t stream)
{
    const float* x   = (const float*)d_in[0];
    const float* Wih = (const float*)d_in[1];
    const float* Whh = (const float*)d_in[2];
    const float* bih = (const float*)d_in[3];
    const float* bhh = (const float*)d_in[4];

    float* ws     = (float*)d_ws;
    float* s_mean = ws + WS_SMEAN;
    float* t_mean = ws + WS_TMEAN;
    float* act    = ws + WS_ACT;
    float* Z      = ws + WS_Z;

    k1a_pool<<<dim3(BB), dim3(256), 0, stream>>>(x, act, s_mean);
    k1b_proj<<<dim3(64, 16), dim3(128), 0, stream>>>(act, Wih, bih, bhh, Z);
    k1c_rnn <<<dim3(BB), dim3(128), 0, stream>>>(Z, Whh, t_mean);
    k2_out  <<<dim3(2048), dim3(256), 0, stream>>>(s_mean, t_mean, (f32x4*)d_out);
}